// Round 3
// baseline (482.654 us; speedup 1.0000x reference)
//
#include <hip/hip_runtime.h>
#include <math.h>

// BeliveMapsNMS: 7x7 same-padded max-pool NMS on [32,4,512,512] f32.
// Outputs (concat flat): mask(0/1 f32), scores_abs, scores_rel.
// R3: vertical-first separable max, same-thread phases.
//  - Thread owns 4 cols x 8 rows: loads its 14 raw rows (coalesced float4),
//    vertical 7-max van Herk in REGISTERS, stages colmax to LDS (padded rows,
//    -inf side pads -> branchless Phase B), horizontal 7-max from 2 LDS reads.
//  - Center values stay in the same thread's registers: ctr global re-read
//    eliminated (-134 MB L2/L3), zero shuffles, one less dep stage.
//  - vmax pass, partials, XCD swizzle, NT stores unchanged from R2.

#define H 512
#define W 512
#define PLANE_ELEMS (H * W)   // 262144
#define TH 16                 // output rows per block
#define NROWS 14              // raw rows per thread strip (8 out + 6 halo)
#define RW 520                // padded LDS row width: 4 + 512 + 4 floats
#define NEG_INF (-INFINITY)
#define VCHUNKS 16            // vmax chunks per plane

typedef float v4f __attribute__((ext_vector_type(4)));  // native vec for nontemporal

__device__ __forceinline__ float4 vmax4(float4 a, float4 b) {
    return make_float4(fmaxf(a.x, b.x), fmaxf(a.y, b.y), fmaxf(a.z, b.z), fmaxf(a.w, b.w));
}

__device__ __forceinline__ void nt_store4(float* p, float a, float b, float c, float d) {
    v4f v = {a, b, c, d};
    __builtin_nontemporal_store(v, (v4f*)p);
}

// ---------------- Pass 1: per-plane max (partials, no atomics) ----------------
__global__ __launch_bounds__(256) void vmax_kernel(const float* __restrict__ in,
                                                   float* __restrict__ partials) {
    const int chunk = blockIdx.x;  // 16 chunks of 16384 floats
    const int plane = blockIdx.y;  // 128 planes
    const float4* p = (const float4*)(in + (size_t)plane * PLANE_ELEMS) + chunk * 4096;
    float4 v[16];
    #pragma unroll
    for (int j = 0; j < 16; ++j) v[j] = p[threadIdx.x + (j << 8)];
    float4 t[8];
    #pragma unroll
    for (int j = 0; j < 8; ++j) t[j] = vmax4(v[j], v[j + 8]);
    #pragma unroll
    for (int j = 0; j < 4; ++j) t[j] = vmax4(t[j], t[j + 4]);
    float4 q = vmax4(vmax4(t[0], t[1]), vmax4(t[2], t[3]));
    float m = fmaxf(fmaxf(q.x, q.y), fmaxf(q.z, q.w));
    #pragma unroll
    for (int o = 32; o > 0; o >>= 1) m = fmaxf(m, __shfl_down(m, o, 64));
    __shared__ float s[4];
    if ((threadIdx.x & 63) == 0) s[threadIdx.x >> 6] = m;
    __syncthreads();
    if (threadIdx.x == 0) {
        partials[(plane << 4) + chunk] = fmaxf(fmaxf(s[0], s[1]), fmaxf(s[2], s[3]));
    }
}

// ---------------- Pass 2: NMS ----------------
__global__ __launch_bounds__(256, 4) void nms_kernel(const float* __restrict__ in,
                                                     const float* __restrict__ partials,
                                                     float* __restrict__ out, int N) {
    // XCD-chunked swizzle: 4096 workgroups = 8 XCDs x 512 (bijective, 4096%8==0).
    const int hwid = blockIdx.x + (blockIdx.y << 5);     // gridDim.x = 32 bands
    const int wg = ((hwid & 7) << 9) + (hwid >> 3);
    const int plane = wg >> 5;
    const int ty0 = (wg & 31) * TH;

    const float* pin = in + (size_t)plane * PLANE_ELEMS;

    __shared__ __align__(16) float sCol[TH * RW];  // 33280 B -> 4 blocks/CU

    const int cg = threadIdx.x & 127;   // column group (4 cols)
    const int strip = threadIdx.x >> 7; // 0/1 -> rows 0..7 / 8..15 of the band
    const int c = cg << 2;
    const int y0 = strip << 3;
    const int gy0 = ty0 + y0;           // first output row of this thread

    // Load 14 raw rows of this thread's 4 columns (independent coalesced float4).
    float4 r[NROWS];
    #pragma unroll
    for (int k = 0; k < NROWS; ++k) {
        const int gy = gy0 + k - 3;
        if (gy >= 0 && gy < H) {
            r[k] = *(const float4*)(pin + (size_t)gy * W + c);
        } else {
            r[k] = make_float4(NEG_INF, NEG_INF, NEG_INF, NEG_INF);
        }
    }

    // Vertical 7-max van Herk: cm[i] = max(r[i..i+6]), i = 0..7.
    float4 A[7];
    A[6] = r[6];
    #pragma unroll
    for (int j = 5; j >= 0; --j) A[j] = vmax4(r[j], A[j + 1]);
    float4 cm[8];
    cm[0] = A[0];
    float4 Bv = r[7];
    cm[1] = vmax4(A[1], Bv);
    #pragma unroll
    for (int j = 2; j <= 6; ++j) { Bv = vmax4(Bv, r[j + 6]); cm[j] = vmax4(A[j], Bv); }
    Bv = vmax4(Bv, r[13]);
    cm[7] = Bv;

    // Stage colmax into padded LDS rows (col x -> float index 4+x).
    #pragma unroll
    for (int i = 0; i < 8; ++i) {
        *(float4*)&sCol[(y0 + i) * RW + 4 + c] = cm[i];
    }
    // Side pads = -inf (branchless horizontal pass).
    if (threadIdx.x < TH) {
        *(float4*)&sCol[threadIdx.x * RW] =
            make_float4(NEG_INF, NEG_INF, NEG_INF, NEG_INF);
    } else if (threadIdx.x < 2 * TH) {
        *(float4*)&sCol[(threadIdx.x - TH) * RW + 4 + W] =
            make_float4(NEG_INF, NEG_INF, NEG_INF, NEG_INF);
    }

    // Plane max from the 16 partials (one cacheline, broadcast).
    float4 pm0 = *(const float4*)&partials[(plane << 4) + 0];
    float4 pm1 = *(const float4*)&partials[(plane << 4) + 4];
    float4 pm2 = *(const float4*)&partials[(plane << 4) + 8];
    float4 pm3 = *(const float4*)&partials[(plane << 4) + 12];
    float4 q = vmax4(vmax4(pm0, pm1), vmax4(pm2, pm3));
    const float vmax = fmaxf(fmaxf(q.x, q.y), fmaxf(q.z, q.w));
    const float rel_thr = 0.05f * vmax;
    const float inv_vmax = 1.0f / vmax;

    __syncthreads();

    float* __restrict__ omask = out;
    float* __restrict__ oabs = out + (size_t)N;
    float* __restrict__ orel = out + 2 * (size_t)N;

    // Horizontal 7-max from 2 aligned LDS reads + own registers; outputs.
    #pragma unroll
    for (int i = 0; i < 8; ++i) {
        const int rowb = (y0 + i) * RW;
        const float4 lo = *(const float4*)&sCol[rowb + c];       // cols c-4..c-1
        const float4 hi = *(const float4*)&sCol[rowb + c + 8];   // cols c+4..c+7
        // window array a[0..9] = cols c-3..c+6
        const float a0 = lo.y, a1 = lo.z, a2 = lo.w;
        const float a3 = cm[i].x, a4 = cm[i].y, a5 = cm[i].z, a6 = cm[i].w;
        const float a7 = hi.x, a8 = hi.y, a9 = hi.z;
        // out[j] = max(a[j..j+6]), j=0..3 (suffix/prefix split at a6)
        const float t5 = fmaxf(a5, a6), t4 = fmaxf(a4, t5), t3 = fmaxf(a3, t4);
        const float t2 = fmaxf(a2, t3), t1 = fmaxf(a1, t2), t0 = fmaxf(a0, t1);
        const float b2 = fmaxf(a7, a8), b3 = fmaxf(b2, a9);
        const float m0 = t0;
        const float m1 = fmaxf(t1, a7);
        const float m2 = fmaxf(t2, b2);
        const float m3 = fmaxf(t3, b3);

        const float4 cc = r[i + 3];   // raw center row, already in registers
        const bool p0 = (m0 == cc.x) & (cc.x > 0.2f) & (cc.x > rel_thr);
        const bool p1 = (m1 == cc.y) & (cc.y > 0.2f) & (cc.y > rel_thr);
        const bool p2 = (m2 == cc.z) & (cc.z > 0.2f) & (cc.z > rel_thr);
        const bool p3 = (m3 == cc.w) & (cc.w > 0.2f) & (cc.w > rel_thr);
        const float a0s = p0 ? cc.x : 0.0f, a1s = p1 ? cc.y : 0.0f;
        const float a2s = p2 ? cc.z : 0.0f, a3s = p3 ? cc.w : 0.0f;
        const int gy = gy0 + i;
        const size_t o = (size_t)plane * PLANE_ELEMS + (size_t)gy * W + c;
        nt_store4(omask + o, p0 ? 1.0f : 0.0f, p1 ? 1.0f : 0.0f,
                             p2 ? 1.0f : 0.0f, p3 ? 1.0f : 0.0f);
        nt_store4(oabs + o, a0s, a1s, a2s, a3s);
        nt_store4(orel + o, a0s * inv_vmax, a1s * inv_vmax,
                            a2s * inv_vmax, a3s * inv_vmax);
    }
}

extern "C" void kernel_launch(void* const* d_in, const int* in_sizes, int n_in,
                              void* d_out, int out_size, void* d_ws, size_t ws_size,
                              hipStream_t stream) {
    const float* in = (const float*)d_in[0];
    float* out = (float*)d_out;
    const int N = in_sizes[0];           // 33554432
    const int planes = N / PLANE_ELEMS;  // 128

    float* partials = (float*)d_ws;      // 128*16 floats = 8 KB

    vmax_kernel<<<dim3(VCHUNKS, planes), 256, 0, stream>>>(in, partials);
    nms_kernel<<<dim3(H / TH, planes), 256, 0, stream>>>(in, partials, out, N);
}